// Round 1
// baseline (434.453 us; speedup 1.0000x reference)
//
#include <hip/hip_runtime.h>
#include <math.h>

#define NPIX   131072      // 8*128*128
#define CCH    256
#define HW     16384       // 128*128
#define BSTR   4194304     // 256*16384 (features b-stride; == 16*262144 for outputs_old)
#define NUMC   21

// ---------------- kernel 1: pseudo labels ----------------
__global__ __launch_bounds__(256) void k_labels(const int* __restrict__ labels,
                                                const float* __restrict__ outputs_old,
                                                int* __restrict__ lab)
{
    int p = blockIdx.x * 256 + threadIdx.x;
    if (p >= NPIX) return;
    int b = p >> 14;
    int rem = p & 16383;
    int h = rem >> 7;
    int w = rem & 127;
    int ld = labels[b * 262144 + (h * 4) * 512 + (w * 4)];
    int out = ld;
    if (ld == 0) {
        const float* oo = outputs_old + (size_t)b * BSTR + (size_t)(h * 4) * 512 + (w * 4);
        float v0 = oo[0];
        float best = (v0 < 0.7f) ? 0.0f : v0;
        int bi = 0;
        #pragma unroll
        for (int c = 1; c < 16; ++c) {
            float v = oo[(size_t)c * 262144];
            v = (v < 0.7f) ? 0.0f : v;
            if (v > best) { best = v; bi = c; }   // strict > == first-occurrence argmax
        }
        out = bi;
    }
    lab[p] = out;
}

// ---------------- kernel 2: per-pixel inverse norms ----------------
__global__ __launch_bounds__(256) void k_norms(const float* __restrict__ fa,
                                               const float* __restrict__ fo,
                                               float* __restrict__ invnA,
                                               float* __restrict__ invnO)
{
    int base = blockIdx.x * 512;           // 512 pixels per block, same b (16384 % 512 == 0)
    int p0 = base + threadIdx.x * 2;
    int b = p0 >> 14;
    int hw = p0 & 16383;
    const float* pa = fa + (size_t)b * BSTR + hw;
    const float* po = fo + (size_t)b * BSTR + hw;
    float sax = 0.f, say = 0.f, sox = 0.f, soy = 0.f;
    #pragma unroll 4
    for (int c = 0; c < CCH; ++c) {
        float2 va = *(const float2*)(pa + (size_t)c * HW);
        float2 vo = *(const float2*)(po + (size_t)c * HW);
        sax += va.x * va.x; say += va.y * va.y;
        sox += vo.x * vo.x; soy += vo.y * vo.y;
    }
    invnA[p0]     = 1.0f / fmaxf(sqrtf(sax), 1e-12f);
    invnA[p0 + 1] = 1.0f / fmaxf(sqrtf(say), 1e-12f);
    invnO[p0]     = 1.0f / fmaxf(sqrtf(sox), 1e-12f);
    invnO[p0 + 1] = 1.0f / fmaxf(sqrtf(soy), 1e-12f);
}

// ---------------- kernel 3: per-class sums ----------------
// thread <-> pixel: class is FIXED per thread; LDS acc padded to 257 so the 21
// class rows land in distinct banks at each channel step.
__global__ __launch_bounds__(256) void k_accum(const float* __restrict__ fa,
                                               const float* __restrict__ fo,
                                               const int* __restrict__ lab,
                                               const float* __restrict__ invnA,
                                               const float* __restrict__ invnO,
                                               float* __restrict__ gsumA,
                                               float* __restrict__ gsumO,
                                               float* __restrict__ gcnt)
{
    __shared__ float accA[NUMC * 257];
    __shared__ float accO[NUMC * 257];
    __shared__ float cnt[NUMC];
    for (int i = threadIdx.x; i < NUMC * 257; i += 256) { accA[i] = 0.f; accO[i] = 0.f; }
    if (threadIdx.x < NUMC) cnt[threadIdx.x] = 0.f;
    __syncthreads();

    int p = blockIdx.x * 256 + threadIdx.x;   // 256 px/block, same b
    int b = p >> 14;
    int hw = p & 16383;
    int k = lab[p];
    float ia = invnA[p];
    float io = invnO[p];
    const float* pa = fa + (size_t)b * BSTR + hw;
    const float* po = fo + (size_t)b * BSTR + hw;
    atomicAdd(&cnt[k], 1.0f);
    int kb = k * 257;
    #pragma unroll 4
    for (int c = 0; c < CCH; ++c) {
        float va = pa[(size_t)c * HW];
        float vo = po[(size_t)c * HW];
        atomicAdd(&accA[kb + c], va * ia);
        atomicAdd(&accO[kb + c], vo * io);
    }
    __syncthreads();
    for (int i = threadIdx.x; i < NUMC * 256; i += 256) {
        int kk = i >> 8, c = i & 255;
        unsafeAtomicAdd(&gsumA[i], accA[kk * 257 + c]);
        unsafeAtomicAdd(&gsumO[i], accO[kk * 257 + c]);
    }
    if (threadIdx.x < NUMC) unsafeAtomicAdd(&gcnt[threadIdx.x], cnt[threadIdx.x]);
}

// ---------------- kernel 4: finalize (tiny) ----------------
__global__ __launch_bounds__(256) void k_final(const float* __restrict__ gsumA,
                                               const float* __restrict__ gsumO,
                                               const float* __restrict__ gcnt,
                                               float* __restrict__ out)
{
    __shared__ float anc[NUMC * 260];
    __shared__ float con[NUMC * 260];
    __shared__ float adc[NUMC * 44];
    __shared__ float cntS[NUMC];
    __shared__ float rowloss[NUMC];
    __shared__ float rowvalid[NUMC];

    if (threadIdx.x < NUMC) cntS[threadIdx.x] = gcnt[threadIdx.x];
    __syncthreads();
    for (int i = threadIdx.x; i < NUMC * 256; i += 256) {
        int k = i >> 8, c = i & 255;
        float cn = cntS[k];
        bool pr = cn > 0.f;
        float d = pr ? cn : 1.f;
        anc[k * 260 + c] = pr ? gsumA[i] / d : 0.f;
        con[k * 260 + c] = pr ? gsumO[i] / d : 0.f;
    }
    __syncthreads();
    // adc[k][j] = dot(anc_k, contrast_j)/T,  contrast = [anc; con]
    for (int pair = threadIdx.x; pair < NUMC * 2 * NUMC; pair += 256) {
        int k = pair / (2 * NUMC);
        int j = pair % (2 * NUMC);
        const float* ar = anc + k * 260;
        const float* br = (j < NUMC) ? (anc + j * 260) : (con + (j - NUMC) * 260);
        float s = 0.f;
        for (int c = 0; c < CCH; c += 4) {
            float4 a4 = *(const float4*)(ar + c);
            float4 b4 = *(const float4*)(br + c);
            s += a4.x * b4.x + a4.y * b4.y + a4.z * b4.z + a4.w * b4.w;
        }
        adc[k * 44 + j] = s / 0.07f;
    }
    __syncthreads();
    if (threadIdx.x < NUMC) {
        int k = threadIdx.x;
        bool pr = cntS[k] > 0.f;
        float neg = 0.f;       // NOTE: faithful to source — negatives use UNshifted logits
        float mx = -1e30f;
        for (int j = 0; j < 2 * NUMC; ++j) {
            int cj = (j < NUMC) ? j : (j - NUMC);
            bool cp = cntS[cj] > 0.f;
            float v = adc[k * 44 + j];
            if (cp) {
                if (v > mx) mx = v;
                if (j != k && j != NUMC + k) neg += expf(v);
            }
        }
        float sh = adc[k * 44 + NUMC + k] - mx;
        float rl = -(sh - logf(expf(sh) + neg));
        rowloss[k] = pr ? rl : 0.f;
        rowvalid[k] = pr ? 1.f : 0.f;
    }
    __syncthreads();
    if (threadIdx.x == 0) {
        float s = 0.f, v = 0.f;
        for (int kk = 0; kk < NUMC; ++kk) { s += rowloss[kk]; v += rowvalid[kk]; }
        out[0] = s / fmaxf(v, 1.f);
    }
}

// ---------------- launch ----------------
extern "C" void kernel_launch(void* const* d_in, const int* in_sizes, int n_in,
                              void* d_out, int out_size, void* d_ws, size_t ws_size,
                              hipStream_t stream) {
    const int*   labels      = (const int*)  d_in[0];
    const float* feats_old   = (const float*)d_in[1];
    const float* feats       = (const float*)d_in[2];
    const float* outputs_old = (const float*)d_in[3];
    // d_in[4] (outputs) and d_in[5] (prototypes) are unused by the reference math.

    float* ws    = (float*)d_ws;
    int*   lab   = (int*)ws;                 // [131072]
    float* invnA = ws + 131072;              // [131072]
    float* invnO = ws + 262144;              // [131072]
    float* gsumA = ws + 393216;              // [21*256]
    float* gsumO = ws + 398592;              // [21*256]
    float* gcnt  = ws + 403968;              // [21]

    hipMemsetAsync(gsumA, 0, (size_t)(NUMC * 256 * 2 + NUMC) * sizeof(float), stream);

    k_labels<<<NPIX / 256, 256, 0, stream>>>(labels, outputs_old, lab);
    k_norms <<<NPIX / 512, 256, 0, stream>>>(feats, feats_old, invnA, invnO);
    k_accum <<<NPIX / 256, 256, 0, stream>>>(feats, feats_old, lab, invnA, invnO,
                                             gsumA, gsumO, gcnt);
    k_final <<<1, 256, 0, stream>>>(gsumA, gsumO, gcnt, (float*)d_out);
}